// Round 1
// baseline (289.774 us; speedup 1.0000x reference)
//
#include <hip/hip_runtime.h>

typedef __attribute__((ext_vector_type(4)))  float fx4;
typedef __attribute__((ext_vector_type(16))) float fx16;
typedef __attribute__((ext_vector_type(8)))  short bf8;

#define SCALE 0.17677669529663687f

__device__ __forceinline__ unsigned short f2bf(float f) {
  unsigned int u = __builtin_bit_cast(unsigned int, f);
  unsigned int r = (u + 0x7fffu + ((u >> 16) & 1u)) >> 16;
  return (unsigned short)r;
}
__device__ __forceinline__ float bf2f(unsigned short u) {
  unsigned int v = ((unsigned int)u) << 16;
  return __builtin_bit_cast(float, v);
}

// ---------------- K0: x NCHW fp32 -> xT NHWC bf16 ----------------
__global__ __launch_bounds__(256) void k0_xT(const float* __restrict__ x,
                                             unsigned short* __restrict__ xT) {
  int h = blockIdx.x, b = blockIdx.y, t = threadIdx.x;
  __shared__ unsigned short tile[128 * 68];
  const float* xrow = x + ((size_t)b * 128 * 4096) + h * 64;
#pragma unroll
  for (int i = 0; i < 8; ++i) {
    int slot = t + i * 256;          // 0..2047
    int c = slot >> 4, wq = slot & 15;
    float4 v = *reinterpret_cast<const float4*>(xrow + (size_t)c * 4096 + wq * 4);
    unsigned short* p = &tile[c * 68 + wq * 4];
    p[0] = f2bf(v.x); p[1] = f2bf(v.y); p[2] = f2bf(v.z); p[3] = f2bf(v.w);
  }
  __syncthreads();
  int w = t >> 2, cc = t & 3;
  unsigned short tmp[32];
#pragma unroll
  for (int j = 0; j < 32; ++j) tmp[j] = tile[(cc * 32 + j) * 68 + w];
  unsigned short* dst = xT + ((size_t)(b * 4096 + h * 64 + w)) * 128 + cc * 32;
#pragma unroll
  for (int q = 0; q < 4; ++q)
    *reinterpret_cast<bf8*>(dst + q * 8) = *reinterpret_cast<bf8*>(tmp + q * 8);
}

// ---------------- K1: conv1x1 (q_map, v_map) -> qT/vT NHWC bf16 (MFMA) -----
__global__ __launch_bounds__(256) void k1_conv(const unsigned short* __restrict__ xT,
    const float* __restrict__ wq, const float* __restrict__ bq,
    const float* __restrict__ wv, const float* __restrict__ bv,
    unsigned short* __restrict__ qT, unsigned short* __restrict__ vT) {
  int pt = blockIdx.x, b = blockIdx.y, qv = blockIdx.z;
  const float* W = qv ? wv : wq;
  const float* bias = qv ? bv : bq;
  unsigned short* out = qv ? vT : qT;
  int t = threadIdx.x, lane = t & 63, wave = t >> 6;
  int wm = wave >> 1, wn = wave & 1;
  int l31 = lane & 31, g2 = lane >> 5;
  fx16 acc[2][2] = {};
  const unsigned short* Abase = xT + ((size_t)b * 4096 + pt * 128) * 128;
#pragma unroll
  for (int ks = 0; ks < 8; ++ks) {
    int kbase = ks * 16 + g2 * 8;
    bf8 a[2], bb[2];
#pragma unroll
    for (int mi = 0; mi < 2; ++mi) {
      int pix = (wm * 2 + mi) * 32 + l31;
      a[mi] = *reinterpret_cast<const bf8*>(Abase + (size_t)pix * 128 + kbase);
    }
#pragma unroll
    for (int ni = 0; ni < 2; ++ni) {
      int oc = (wn * 2 + ni) * 32 + l31;
      const float* wp = W + oc * 128 + kbase;
      float4 w0 = *reinterpret_cast<const float4*>(wp);
      float4 w1 = *reinterpret_cast<const float4*>(wp + 4);
      bf8 r;
      r[0]=(short)f2bf(w0.x); r[1]=(short)f2bf(w0.y); r[2]=(short)f2bf(w0.z); r[3]=(short)f2bf(w0.w);
      r[4]=(short)f2bf(w1.x); r[5]=(short)f2bf(w1.y); r[6]=(short)f2bf(w1.z); r[7]=(short)f2bf(w1.w);
      bb[ni] = r;
    }
#pragma unroll
    for (int mi = 0; mi < 2; ++mi)
#pragma unroll
      for (int ni = 0; ni < 2; ++ni)
        acc[mi][ni] = __builtin_amdgcn_mfma_f32_32x32x16_bf16(a[mi], bb[ni], acc[mi][ni], 0, 0, 0);
  }
#pragma unroll
  for (int ni = 0; ni < 2; ++ni) {
    int oc = (wn * 2 + ni) * 32 + l31;
    float bsv = bias[oc];
#pragma unroll
    for (int mi = 0; mi < 2; ++mi) {
#pragma unroll
      for (int r = 0; r < 16; ++r) {
        int row = (r & 3) + 8 * (r >> 2) + 4 * g2;
        int pix = pt * 128 + (wm * 2 + mi) * 32 + row;
        out[((size_t)b * 4096 + pix) * 128 + oc] = f2bf(acc[mi][ni][r] + bsv);
      }
    }
  }
}

// ---------------- K2: depthwise 5x5 on vT -> lepe NHWC fp32 ----------------
__global__ __launch_bounds__(256) void k2_lepe(const unsigned short* __restrict__ vT,
    const float* __restrict__ wl5, const float* __restrict__ bl,
    float* __restrict__ lepe) {
  int strip = blockIdx.x, hd = blockIdx.y, b = blockIdx.z;
  int t = threadIdx.x;
  __shared__ unsigned short tile[12 * 64 * 34];  // [row 12][w 64][c 32+pad2]
  int h0 = strip * 8;
#pragma unroll
  for (int i = 0; i < 12; ++i) {
    int slot = t + i * 256;                 // 0..3071
    int r = slot >> 8;                      // 0..11
    int rem = slot & 255;
    int w = rem >> 2, cc = rem & 3;         // cc*8 channels
    int h = h0 - 2 + r;
    unsigned short vv[8];
    if (h >= 0 && h < 64) {
      *reinterpret_cast<bf8*>(vv) = *reinterpret_cast<const bf8*>(
          vT + ((size_t)b * 4096 + h * 64 + w) * 128 + hd * 32 + cc * 8);
    } else {
#pragma unroll
      for (int j = 0; j < 8; ++j) vv[j] = 0;
    }
    unsigned int* dst = reinterpret_cast<unsigned int*>(&tile[(r * 64 + w) * 34 + cc * 8]);
#pragma unroll
    for (int j = 0; j < 4; ++j)
      dst[j] = ((unsigned int)vv[2 * j + 1] << 16) | (unsigned int)vv[2 * j];
  }
  __syncthreads();
  int c2 = t & 15, w16 = t >> 4;
  int c = c2 * 2;
  float wt0[25], wt1[25];
#pragma unroll
  for (int i = 0; i < 25; ++i) {
    wt0[i] = wl5[(hd * 32 + c) * 25 + i];
    wt1[i] = wl5[(hd * 32 + c + 1) * 25 + i];
  }
  float b0 = bl[hd * 32 + c], b1 = bl[hd * 32 + c + 1];
  for (int hh = 0; hh < 8; ++hh) {
    for (int wi = 0; wi < 4; ++wi) {
      int w = w16 * 4 + wi;
      float a0 = b0, a1 = b1;
#pragma unroll
      for (int dy = 0; dy < 5; ++dy) {
        int rr = hh + dy;
#pragma unroll
        for (int dx = 0; dx < 5; ++dx) {
          int wx = w + dx - 2;
          if (wx < 0 || wx >= 64) continue;
          unsigned int pr = *reinterpret_cast<const unsigned int*>(&tile[(rr * 64 + wx) * 34 + c]);
          float v0 = bf2f((unsigned short)(pr & 0xffffu));
          float v1 = bf2f((unsigned short)(pr >> 16));
          a0 += v0 * wt0[dy * 5 + dx];
          a1 += v1 * wt1[dy * 5 + dx];
        }
      }
      float2 st; st.x = a0; st.y = a1;
      *reinterpret_cast<float2*>(&lepe[((size_t)b * 4096 + (h0 + hh) * 64 + w) * 128 + hd * 32 + c]) = st;
    }
  }
}

// helper: load 8 bf16 + 8 fp32, add, scale, convert to bf16x8 fragment
__device__ __forceinline__ bf8 frag_add(const unsigned short* xp, const float* lp, float scale) {
  bf8 xv = *reinterpret_cast<const bf8*>(xp);
  float4 l0 = *reinterpret_cast<const float4*>(lp);
  float4 l1 = *reinterpret_cast<const float4*>(lp + 4);
  bf8 r;
  r[0] = (short)f2bf((bf2f((unsigned short)xv[0]) + l0.x) * scale);
  r[1] = (short)f2bf((bf2f((unsigned short)xv[1]) + l0.y) * scale);
  r[2] = (short)f2bf((bf2f((unsigned short)xv[2]) + l0.z) * scale);
  r[3] = (short)f2bf((bf2f((unsigned short)xv[3]) + l0.w) * scale);
  r[4] = (short)f2bf((bf2f((unsigned short)xv[4]) + l1.x) * scale);
  r[5] = (short)f2bf((bf2f((unsigned short)xv[5]) + l1.y) * scale);
  r[6] = (short)f2bf((bf2f((unsigned short)xv[6]) + l1.z) * scale);
  r[7] = (short)f2bf((bf2f((unsigned short)xv[7]) + l1.w) * scale);
  return r;
}

// ---------------- K3: fused attention per (window, head) ----------------
__global__ __launch_bounds__(256, 2) void k3_attn(
    const unsigned short* __restrict__ xT, const unsigned short* __restrict__ qT,
    const unsigned short* __restrict__ vT, const float* __restrict__ lepe,
    const float* __restrict__ ai, const float* __restrict__ temp,
    float* __restrict__ attn, float* __restrict__ out_win) {
  int w = blockIdx.x;           // window 0..255
  int hd = blockIdx.y;          // head 0..3
  int b = w >> 4, ww = w & 15;
  int t = threadIdx.x, lane = t & 63, wave = t >> 6;
  int l15 = lane & 15, g = lane >> 4;
  __shared__ unsigned short Vt[32 * 264];   // V transposed: [d][l]

  // stage Vt: thread t handles window row l = t
  {
    int l = t;
    int pix = (l >> 2) * 64 + ww * 4 + (l & 3);
    const unsigned short* src = vT + ((size_t)b * 4096 + pix) * 128 + hd * 32;
    unsigned short vv[32];
#pragma unroll
    for (int q = 0; q < 4; ++q)
      *reinterpret_cast<bf8*>(vv + q * 8) = *reinterpret_cast<const bf8*>(src + q * 8);
#pragma unroll
    for (int d = 0; d < 32; ++d) Vt[d * 264 + l] = vv[d];
  }
  __syncthreads();
  float tHd = temp[hd];

  // hoist K fragments (B operand): K = x + lepe
  bf8 kf[16];
#pragma unroll
  for (int nt = 0; nt < 16; ++nt) {
    int kpos = nt * 16 + l15;
    int pix = (kpos >> 2) * 64 + ww * 4 + (kpos & 3);
    size_t off = ((size_t)b * 4096 + pix) * 128 + hd * 32 + g * 8;
    kf[nt] = frag_add(xT + off, lepe + off, 1.0f);
  }

  const size_t aBase = ((size_t)w * 4 + hd) * 256 * 256;
  const float* aiB = ai + aBase;
  float* atB = attn + aBase;
  float* owB = out_win + ((size_t)w * 4 + hd) * 256 * 32;

  for (int pass = 0; pass < 4; ++pass) {
    int qbase = (pass * 4 + wave) * 16;
    // Q fragment (A operand): (q_map + lepe) * SCALE
    bf8 qf;
    {
      int qrow = qbase + l15;
      int pix = (qrow >> 2) * 64 + ww * 4 + (qrow & 3);
      size_t off = ((size_t)b * 4096 + pix) * 128 + hd * 32 + g * 8;
      qf = frag_add(qT + off, lepe + off, SCALE);
    }
    fx4 acc[16];
#pragma unroll
    for (int nt = 0; nt < 16; ++nt) { acc[nt][0]=0.f; acc[nt][1]=0.f; acc[nt][2]=0.f; acc[nt][3]=0.f; }
#pragma unroll
    for (int nt = 0; nt < 16; ++nt)
      acc[nt] = __builtin_amdgcn_mfma_f32_16x16x32_bf16(qf, kf[nt], acc[nt], 0, 0, 0);

    // softmax: lane holds rows qbase + g*4 + r  (r=0..3), cols nt*16 + l15
    float inv[4];
#pragma unroll
    for (int r = 0; r < 4; ++r) {
      float m = acc[0][r];
#pragma unroll
      for (int nt = 1; nt < 16; ++nt) m = fmaxf(m, acc[nt][r]);
      m = fmaxf(m, __shfl_xor(m, 1));
      m = fmaxf(m, __shfl_xor(m, 2));
      m = fmaxf(m, __shfl_xor(m, 4));
      m = fmaxf(m, __shfl_xor(m, 8));
      float s = 0.f;
#pragma unroll
      for (int nt = 0; nt < 16; ++nt) {
        float p = __expf(acc[nt][r] - m);
        acc[nt][r] = p;
        s += p;
      }
      s += __shfl_xor(s, 1); s += __shfl_xor(s, 2);
      s += __shfl_xor(s, 4); s += __shfl_xor(s, 8);
      inv[r] = 1.0f / s;
    }

    // attn = p/sum + t*ai : stream read + write (64B granule per 4-row group)
#pragma unroll
    for (int nt = 0; nt < 16; ++nt) {
#pragma unroll
      for (int r = 0; r < 4; ++r) {
        int row = qbase + g * 4 + r;
        int col = nt * 16 + l15;
        size_t idx = (size_t)row * 256 + col;
        atB[idx] = acc[nt][r] * inv[r] + tHd * aiB[idx];
      }
    }
    // make the stores visible before PV re-reads them
    asm volatile("s_waitcnt vmcnt(0)" ::: "memory");

    // PV: out(16x32) = attn(16x256) @ V(256x32)
    fx4 oacc[2];
    oacc[0][0]=0.f;oacc[0][1]=0.f;oacc[0][2]=0.f;oacc[0][3]=0.f;
    oacc[1][0]=0.f;oacc[1][1]=0.f;oacc[1][2]=0.f;oacc[1][3]=0.f;
#pragma unroll
    for (int ks = 0; ks < 8; ++ks) {
      const float* ap = atB + (size_t)(qbase + l15) * 256 + ks * 32 + g * 8;
      float4 a0 = *reinterpret_cast<const float4*>(ap);
      float4 a1 = *reinterpret_cast<const float4*>(ap + 4);
      bf8 af;
      af[0]=(short)f2bf(a0.x); af[1]=(short)f2bf(a0.y); af[2]=(short)f2bf(a0.z); af[3]=(short)f2bf(a0.w);
      af[4]=(short)f2bf(a1.x); af[5]=(short)f2bf(a1.y); af[6]=(short)f2bf(a1.z); af[7]=(short)f2bf(a1.w);
#pragma unroll
      for (int nt2 = 0; nt2 < 2; ++nt2) {
        bf8 vf = *reinterpret_cast<const bf8*>(&Vt[(nt2 * 16 + l15) * 264 + ks * 32 + g * 8]);
        oacc[nt2] = __builtin_amdgcn_mfma_f32_16x16x32_bf16(af, vf, oacc[nt2], 0, 0, 0);
      }
    }
#pragma unroll
    for (int nt2 = 0; nt2 < 2; ++nt2)
#pragma unroll
      for (int r = 0; r < 4; ++r) {
        int row = qbase + g * 4 + r;
        owB[(size_t)row * 32 + nt2 * 16 + l15] = oacc[nt2][r];
      }
  }
}

// ---------------- K4: out0 = un-window(out_win) + lepe ----------------
__global__ __launch_bounds__(256) void k4_out(const float* __restrict__ out_win,
    const float* __restrict__ lepe, float* __restrict__ out0) {
  int h = blockIdx.x, b = blockIdx.y, t = threadIdx.x;
  __shared__ float winb[16 * 533];   // strides: hd 33, wl 133, ww 533
  __shared__ float lep[64 * 129];
#pragma unroll
  for (int i = 0; i < 8; ++i) {
    int slot = t + i * 256;          // 0..2047 float4 slots
    int ww = slot >> 7, rem = slot & 127;
    int hdq = rem >> 5, rem2 = rem & 31;
    int wl = rem2 >> 3, dq = rem2 & 7;
    float4 v = *reinterpret_cast<const float4*>(
        out_win + (((size_t)(b * 16 + ww) * 4 + hdq) * 256 + h * 4 + wl) * 32 + dq * 4);
    float* p = &winb[ww * 533 + wl * 133 + hdq * 33 + dq * 4];
    p[0] = v.x; p[1] = v.y; p[2] = v.z; p[3] = v.w;
  }
#pragma unroll
  for (int i = 0; i < 8; ++i) {
    int slot = t + i * 256;
    int w = slot >> 5, cq = slot & 31;
    float4 v = *reinterpret_cast<const float4*>(
        lepe + ((size_t)b * 4096 + h * 64 + w) * 128 + cq * 4);
    float* p = &lep[w * 129 + cq * 4];
    p[0] = v.x; p[1] = v.y; p[2] = v.z; p[3] = v.w;
  }
  __syncthreads();
  int w = t & 63, cg = t >> 6;
#pragma unroll
  for (int ci = 0; ci < 32; ++ci) {
    int c = cg * 32 + ci;
    float val = winb[(w >> 2) * 533 + (w & 3) * 133 + (c >> 5) * 33 + (c & 31)] + lep[w * 129 + c];
    out0[((size_t)(b * 128 + c) * 64 + h) * 64 + w] = val;
  }
}

extern "C" void kernel_launch(void* const* d_in, const int* in_sizes, int n_in,
                              void* d_out, int out_size, void* d_ws, size_t ws_size,
                              hipStream_t stream) {
  const float* x    = (const float*)d_in[0];
  const float* ai   = (const float*)d_in[1];
  const float* wq   = (const float*)d_in[2];
  const float* bq   = (const float*)d_in[3];
  const float* wv   = (const float*)d_in[4];
  const float* bv   = (const float*)d_in[5];
  const float* wl5  = (const float*)d_in[6];
  const float* bl   = (const float*)d_in[7];
  const float* temp = (const float*)d_in[8];
  float* out0 = (float*)d_out;
  float* attn = out0 + 8388608;

  char* ws = (char*)d_ws;
  unsigned short* xT = (unsigned short*)(ws);                 // 16 MB bf16
  unsigned short* qT = (unsigned short*)(ws + 16777216);      // 16 MB bf16
  unsigned short* vT = (unsigned short*)(ws + 33554432);      // 16 MB bf16
  float* lepe        = (float*)(ws + 50331648);               // 32 MB fp32 NHWC
  float* ow          = (float*)(ws + 83886080);               // 32 MB fp32 windowed

  k0_xT  <<<dim3(64, 16),    256, 0, stream>>>(x, xT);
  k1_conv<<<dim3(32, 16, 2), 256, 0, stream>>>(xT, wq, bq, wv, bv, qT, vT);
  k2_lepe<<<dim3(8, 4, 16),  256, 0, stream>>>(vT, wl5, bl, lepe);
  k3_attn<<<dim3(256, 4),    256, 0, stream>>>(xT, qT, vT, lepe, ai, temp, attn, ow);
  k4_out <<<dim3(64, 16),    256, 0, stream>>>(ow, lepe, out0);
}